// Round 1
// baseline (350.380 us; speedup 1.0000x reference)
//
#include <hip/hip_runtime.h>
#include <hip/hip_bf16.h>

#define BB   16
#define CIN  256
#define TN   4096
#define LOUT 4110
#define FTS  4224   // first_t per-batch stride (ints)

// ---------------- workspace layout (bytes) ----------------
// featT  bf16 [B][T][256]        0        .. 33554432
// wT2    f32  [256][512]         33554432 (GLU-paired columns)
// wp0T   f32  [(2*31)][32] pad   34078720
// wp1T   f32  [(32*15)][32]      34086912
// xx     f32  [B][T]             34148352
// wts    f32  [B][T]             34410496
// mvr    f32  [B][T]             34672640
// poses  f32  [B][T]             34934784
// firstT int  [B][4224]          35196928   (end 35467264)

// ======================= K0: weight prep =======================
__global__ __launch_bounds__(256) void k0_prep(
    const float* __restrict__ conv1_w, const float* __restrict__ p0_w,
    const float* __restrict__ p1_w, float* __restrict__ wT2,
    float* __restrict__ wp0T, float* __restrict__ wp1T) {
  int bid = blockIdx.x, tid = threadIdx.x;
  if (bid < 512) {
    int idx = bid * 256 + tid;          // < 131072
    int n = idx & 511, ci = idx >> 9;
    int nb = n >> 6, j = n & 63;
    int co = (j < 32) ? (nb * 32 + j) : (256 + nb * 32 + (j - 32));
    wT2[idx] = conv1_w[co * 256 + ci];
  } else {
    int idx = (bid - 512) * 256 + tid;  // < 15360
    if (idx < 1984) {
      int ch = idx & 31, rem = idx >> 5;
      int ic = rem / 31, k = rem % 31;
      wp0T[idx] = p0_w[(ch * 2 + ic) * 31 + k];
    }
    if (idx < 15360) {
      int ch = idx & 31, rem = idx >> 5;
      int ic = rem / 15, k = rem % 15;
      wp1T[idx] = p1_w[(ch * 32 + ic) * 15 + k];
    }
  }
}

// ========== K1: conv1(1x1) GEMM + BN + GLU (+xx)  ==========
// grid (8 nblk, 64 t-tiles, 16 b), 256 thr. Tile 64t x 64n, 4x4 micro.
__global__ __launch_bounds__(256) void k1_gemm(
    const float* __restrict__ x, const float* __restrict__ wT2,
    const float* __restrict__ bn1_g, const float* __restrict__ bn1_b,
    const float* __restrict__ bn1_m, const float* __restrict__ bn1_v,
    const float* __restrict__ w1x1,
    __hip_bfloat16* __restrict__ featT, float* __restrict__ xxo) {
  int nblk = blockIdx.x;
  int t0 = blockIdx.y * 64;
  int b = blockIdx.z;
  __shared__ float As[32][64];
  __shared__ float Ws[32][64];
  __shared__ float ebuf[64][65];
  __shared__ float xxs[4][64];
  int tid = threadIdx.x;
  int tm = tid & 15, tn = tid >> 4;
  float acc[4][4];
#pragma unroll
  for (int i = 0; i < 4; ++i)
#pragma unroll
    for (int j = 0; j < 4; ++j) acc[i][j] = 0.f;
  float xxa = 0.f;
  int wv = tid >> 6, ml = tid & 63;
  const float* xb = x + (size_t)b * CIN * TN;

  for (int kc = 0; kc < 8; ++kc) {
    int k0 = kc * 32;
#pragma unroll
    for (int s = 0; s < 2; ++s) {
      int idx = tid + s * 256;
      int k = idx >> 4, mq = idx & 15;
      float4 v = *(const float4*)(xb + (size_t)(k0 + k) * TN + t0 + mq * 4);
      *(float4*)(&As[k][mq * 4]) = v;
      float4 w4 = *(const float4*)(wT2 + (size_t)(k0 + k) * 512 + nblk * 64 + mq * 4);
      *(float4*)(&Ws[k][mq * 4]) = w4;
    }
    __syncthreads();
#pragma unroll 8
    for (int k = 0; k < 32; ++k) {
      float4 a4 = *(const float4*)(&As[k][tm * 4]);
      float4 b4 = *(const float4*)(&Ws[k][tn * 4]);
      float aa[4] = {a4.x, a4.y, a4.z, a4.w};
      float bb2[4] = {b4.x, b4.y, b4.z, b4.w};
#pragma unroll
      for (int i = 0; i < 4; ++i)
#pragma unroll
        for (int j = 0; j < 4; ++j) acc[i][j] = fmaf(aa[i], bb2[j], acc[i][j]);
    }
    if (nblk == 0) {
#pragma unroll
      for (int k = 0; k < 8; ++k)
        xxa = fmaf(As[wv * 8 + k][ml], w1x1[k0 + wv * 8 + k], xxa);
    }
    __syncthreads();
  }
#pragma unroll
  for (int i = 0; i < 4; ++i)
#pragma unroll
    for (int j = 0; j < 4; ++j) ebuf[tm * 4 + i][tn * 4 + j] = acc[i][j];
  if (nblk == 0) xxs[wv][ml] = xxa;
  __syncthreads();
#pragma unroll
  for (int it = 0; it < 8; ++it) {
    int idx = tid + it * 256;          // 2048 = 64 t x 32 ch
    int j = idx & 31, m = idx >> 5;
    float a = ebuf[m][j], g = ebuf[m][32 + j];
    int ca = nblk * 32 + j, cg = ca + 256;
    float av = (a - bn1_m[ca]) * (bn1_g[ca] * rsqrtf(bn1_v[ca] + 1e-3f)) + bn1_b[ca];
    float gv = (g - bn1_m[cg]) * (bn1_g[cg] * rsqrtf(bn1_v[cg] + 1e-3f)) + bn1_b[cg];
    float fv = av / (1.f + __expf(-gv));
    featT[((size_t)b * TN + t0 + m) * 256 + ca] = __float2bfloat16(fv);
  }
  if (nblk == 0 && tid < 64)
    xxo[b * TN + t0 + tid] = xxs[0][tid] + xxs[1][tid] + xxs[2][tid] + xxs[3][tid];
}

// ========== K2: fused predictor (p0->bn->silu->p1->bn->silu->p2->sigmoid) ==========
// grid (32 t-tiles of 128, 16 b), 256 thr.
__global__ __launch_bounds__(256) void k2_pred(
    const float* __restrict__ xx,
    const float* __restrict__ wp0T, const float* __restrict__ p0_b,
    const float* __restrict__ p0g, const float* __restrict__ p0bb,
    const float* __restrict__ p0m, const float* __restrict__ p0v,
    const float* __restrict__ wp1T, const float* __restrict__ p1_b,
    const float* __restrict__ p1g, const float* __restrict__ p1bb,
    const float* __restrict__ p1m, const float* __restrict__ p1v,
    const float* __restrict__ p2_w, const float* __restrict__ p2_b,
    const float* __restrict__ norm_mean,
    float* __restrict__ wts, float* __restrict__ mvr) {
  int t0 = blockIdx.x * 128;
  int b = blockIdx.y;
  __shared__ float xin[2][186];   // t in [t0-29, t0+157)
  __shared__ float h0s[32][176];  // t = t0-14+i, valid i<156 (pad for vec reads)
  __shared__ float h1s[32][142];  // t = t0-7+i,  i<142
  int tid = threadIdx.x;
  for (int idx = tid; idx < 186; idx += 256) {
    int t = t0 - 29 + idx;
    float v = (t >= 0 && t < TN) ? xx[b * TN + t] : 0.f;
    xin[0][idx] = v;
    xin[1][idx] = v * v;
  }
  __syncthreads();
  {  // p0: K=31, 2 in-ch
    int ch = tid & 31, tq = tid >> 5;
    float sc = p0g[ch] * rsqrtf(p0v[ch] + 1e-5f);
    float mb = p0m[ch], bbn = p0bb[ch], bias = p0_b[ch];
    for (int i = tq; i < 156; i += 8) {
      float a = bias;
#pragma unroll
      for (int ic = 0; ic < 2; ++ic)
#pragma unroll
        for (int k = 0; k < 31; ++k)
          a = fmaf(wp0T[(ic * 31 + k) * 32 + ch], xin[ic][i + k], a);
      float v = (a - mb) * sc + bbn;
      h0s[ch][i] = v / (1.f + __expf(-v));
    }
  }
  __syncthreads();
  {  // p1: K=15, 32 in-ch  (hot loop: row in regs)
    int ch = tid & 31, tq = tid >> 5;
    int i0 = tq * 20;  // 8 groups x 20 >= 142 (16B-aligned vec reads)
    float sc = p1g[ch] * rsqrtf(p1v[ch] + 1e-5f);
    float mb = p1m[ch], bbn = p1bb[ch], bias = p1_b[ch];
    float a[20];
#pragma unroll
    for (int j = 0; j < 20; ++j) a[j] = bias;
    for (int ic = 0; ic < 32; ++ic) {
      float r[36];
#pragma unroll
      for (int q = 0; q < 9; ++q) {
        float4 t4 = *(const float4*)(&h0s[ic][i0 + q * 4]);
        r[q * 4 + 0] = t4.x; r[q * 4 + 1] = t4.y;
        r[q * 4 + 2] = t4.z; r[q * 4 + 3] = t4.w;
      }
      float w[15];
#pragma unroll
      for (int k = 0; k < 15; ++k) w[k] = wp1T[(ic * 15 + k) * 32 + ch];
#pragma unroll
      for (int j = 0; j < 20; ++j)
#pragma unroll
        for (int k = 0; k < 15; ++k) a[j] = fmaf(w[k], r[j + k], a[j]);
    }
#pragma unroll
    for (int j = 0; j < 20; ++j) {
      int i = i0 + j;
      if (i < 142) {
        float v = (a[j] - mb) * sc + bbn;
        h1s[ch][i] = v / (1.f + __expf(-v));
      }
    }
  }
  __syncthreads();
  {  // p2: K=15, 2 out-ch -> sigmoids
    int ch = tid >> 7, i = tid & 127;
    float a = p2_b[ch];
    for (int ic = 0; ic < 32; ++ic)
#pragma unroll
      for (int k = 0; k < 15; ++k)
        a = fmaf(p2_w[(ch * 32 + ic) * 15 + k], h1s[ic][i + k], a);
    float s = 1.f / (1.f + __expf(-a));
    int t = t0 + i;
    if (ch == 0) wts[b * TN + t] = s;
    else         mvr[b * TN + t] = s * norm_mean[0];
  }
}

// ========== K3: per-batch renorm + cumsum + first_t ==========
__global__ __launch_bounds__(256) void k3_scan(const float* __restrict__ mvr,
                                               float* __restrict__ poses,
                                               int* __restrict__ firstT) {
  int b = blockIdx.x, tid = threadIdx.x;
  __shared__ float csum[256];
  __shared__ int shlast;
  float v[16];
  const float* src = mvr + b * TN + tid * 16;
  float run = 0.f;
#pragma unroll
  for (int j = 0; j < 16; ++j) { run += src[j]; v[j] = run; }
  csum[tid] = run;
  __syncthreads();
  for (int off = 1; off < 256; off <<= 1) {
    float tv = (tid >= off) ? csum[tid - off] : 0.f;
    __syncthreads();
    csum[tid] += tv;
    __syncthreads();
  }
  float incl = csum[tid];
  float total = csum[255];
  float excl = incl - run;
  __syncthreads();
  float rn = total * (1.0f / 4096.0f);
  float inv = (rn > 1.0f) ? 1.0f / rn : 1.0f;
  float p16[16];
  float* pd = poses + b * TN + tid * 16;
#pragma unroll
  for (int j = 0; j < 16; ++j) { p16[j] = (excl + v[j]) * inv; pd[j] = p16[j]; }
  csum[tid] = p16[15];  // boundary pose for next thread (bit-exact w/ stored)
  __syncthreads();
  int* ft = firstT + b * FTS;
  int prevf = (tid == 0) ? -1 : min((int)floorf(csum[tid - 1]), 4220);
  int f = prevf;
#pragma unroll
  for (int j = 0; j < 16; ++j) {
    f = min((int)floorf(p16[j]), 4220);
    for (int l = prevf + 1; l <= f; ++l) ft[l] = tid * 16 + j;
    prevf = f;
  }
  if (tid == 255) shlast = f;
  __syncthreads();
  for (int l = shlast + 1 + tid; l < FTS; l += 256) ft[l] = TN;
}

// ========== K4: gather-formulated scatter pool (atomic-free) ==========
// grid (257 l-tiles of 16, 16 b), 256 thr (one per channel).
__global__ __launch_bounds__(256) void k4_gather(
    const __hip_bfloat16* __restrict__ featT, const float* __restrict__ wts,
    const float* __restrict__ poses, const int* __restrict__ firstT,
    float* __restrict__ out) {
  int l0 = blockIdx.x * 16;
  int b = blockIdx.y;
  __shared__ float acc[16][258];
  int tid = threadIdx.x;
  for (int idx = tid; idx < 16 * 258; idx += 256) ((float*)acc)[idx] = 0.f;
  const int* ft = firstT + b * FTS;
  int ts = ft[l0 == 0 ? 0 : l0 - 1];
  int te = ft[l0 + 16];
  __syncthreads();
  int c = tid;
  for (int t = ts; t < te; ++t) {
    float p = poses[b * TN + t];
    float wg = wts[b * TN + t];
    float fv = __bfloat162float(featT[((size_t)b * TN + t) * 256 + c]);
    int fi = (int)floorf(p);
    float w2 = p - (float)fi;
    float w1 = 1.f - w2;
    float fw = fv * wg;
    int r1 = fi - l0;
    if (r1 >= 0 && r1 < 16) acc[r1][c] += w1 * fw;
    int r2 = r1 + 1;
    if (r2 >= 0 && r2 < 16) acc[r2][c] += w2 * fw;
  }
  __syncthreads();
  for (int idx = tid; idx < 4096; idx += 256) {
    int c2 = idx >> 4, r = idx & 15;
    int l = l0 + r;
    if (l < LOUT) out[((size_t)b * 256 + c2) * LOUT + l] = acc[r][c2];
  }
}

// ======================= launch =======================
extern "C" void kernel_launch(void* const* d_in, const int* in_sizes, int n_in,
                              void* d_out, int out_size, void* d_ws, size_t ws_size,
                              hipStream_t stream) {
  const float* x       = (const float*)d_in[0];
  const float* conv1_w = (const float*)d_in[1];
  const float* bn1_g   = (const float*)d_in[2];
  const float* bn1_b   = (const float*)d_in[3];
  const float* bn1_m   = (const float*)d_in[4];
  const float* bn1_v   = (const float*)d_in[5];
  const float* w1x1    = (const float*)d_in[6];
  const float* p0_w    = (const float*)d_in[7];
  const float* p0_b    = (const float*)d_in[8];
  const float* p0g     = (const float*)d_in[9];
  const float* p0bb    = (const float*)d_in[10];
  const float* p0m     = (const float*)d_in[11];
  const float* p0v     = (const float*)d_in[12];
  const float* p1_w    = (const float*)d_in[13];
  const float* p1_b    = (const float*)d_in[14];
  const float* p1g     = (const float*)d_in[15];
  const float* p1bb    = (const float*)d_in[16];
  const float* p1m     = (const float*)d_in[17];
  const float* p1v     = (const float*)d_in[18];
  const float* p2_w    = (const float*)d_in[19];
  const float* p2_b    = (const float*)d_in[20];
  const float* nmean   = (const float*)d_in[21];

  char* ws = (char*)d_ws;
  __hip_bfloat16* featT = (__hip_bfloat16*)ws;
  float* wT2   = (float*)(ws + 33554432);
  float* wp0T  = (float*)(ws + 34078720);
  float* wp1T  = (float*)(ws + 34086912);
  float* xx    = (float*)(ws + 34148352);
  float* wts   = (float*)(ws + 34410496);
  float* mvr   = (float*)(ws + 34672640);
  float* poses = (float*)(ws + 34934784);
  int*   firstT= (int*)  (ws + 35196928);
  float* out   = (float*)d_out;

  k0_prep<<<dim3(572), dim3(256), 0, stream>>>(conv1_w, p0_w, p1_w, wT2, wp0T, wp1T);
  k1_gemm<<<dim3(8, 64, 16), dim3(256), 0, stream>>>(x, wT2, bn1_g, bn1_b, bn1_m,
                                                     bn1_v, w1x1, featT, xx);
  k2_pred<<<dim3(32, 16), dim3(256), 0, stream>>>(xx, wp0T, p0_b, p0g, p0bb, p0m, p0v,
                                                  wp1T, p1_b, p1g, p1bb, p1m, p1v,
                                                  p2_w, p2_b, nmean, wts, mvr);
  k3_scan<<<dim3(16), dim3(256), 0, stream>>>(mvr, poses, firstT);
  k4_gather<<<dim3(257, 16), dim3(256), 0, stream>>>(featT, wts, poses, firstT, out);
}

// Round 2
// 169.828 us; speedup vs baseline: 2.0631x; 2.0631x over previous
//
#include <hip/hip_runtime.h>
#include <hip/hip_bf16.h>

#define BB   16
#define CIN  256
#define TN   4096
#define LOUT 4110
#define FTS  4224   // first_t per-batch stride (ints)

typedef __attribute__((ext_vector_type(8))) short s16x8;
typedef __attribute__((ext_vector_type(4))) float f32x4;

// ---------------- workspace layout (bytes) ----------------
// featT  bf16 [B][T][256]        0          (33554432)
// wBpk   bf16 fragment-packed    33554432   (262144)
// bnp    float4[256]             33816576   (4096)
// wp0T   f32                     33820672   (8192)
// wp1T   f32                     33828864   (61440)
// xx     f32  [B][T]             33890304
// wts    f32  [B][T]             34152448
// mvr    f32  [B][T]             34414592
// poses  f32  [B][T]             34676736
// firstT int  [B][4224]          34938880   (end 35209216)
// xT bf16 [B][T][256] lives in d_out (33.5MB < 67.3MB; K4 rewrites all of d_out)

// ======================= K0: weight prep =======================
__global__ __launch_bounds__(256) void k0_prep(
    const float* __restrict__ conv1_w, const float* __restrict__ p0_w,
    const float* __restrict__ p1_w,
    const float* __restrict__ bn1_g, const float* __restrict__ bn1_b,
    const float* __restrict__ bn1_m, const float* __restrict__ bn1_v,
    short* __restrict__ wBpk, float4* __restrict__ bnp,
    float* __restrict__ wp0T, float* __restrict__ wp1T) {
  int bid = blockIdx.x, tid = threadIdx.x;
  if (bid < 512) {
    // wBpk flat: ((n16*8 + ks)*64 + l)*8 + i ; value = Wpacked[n16*16+(l&15)][ks*32+(l>>4)*8+i]
    int e = bid * 256 + tid;               // 0..131071
    int i = e & 7, l = (e >> 3) & 63, ks = (e >> 9) & 7, n16 = e >> 12;
    int n = n16 * 16 + (l & 15);           // packed col 0..511
    int j = n & 63;
    int co = (j < 32) ? ((n >> 6) * 32 + j) : (256 + (n >> 6) * 32 + (j - 32));
    int ci = ks * 32 + (l >> 4) * 8 + i;
    __hip_bfloat16 hv = __float2bfloat16(conv1_w[co * 256 + ci]);
    wBpk[e] = *(short*)&hv;
  } else {
    int idx = (bid - 512) * 256 + tid;     // 0..15615
    if (idx < 1984) {
      int ch = idx & 31, rem = idx >> 5;
      int ic = rem / 31, k = rem % 31;
      wp0T[idx] = p0_w[(ch * 2 + ic) * 31 + k];
    }
    if (idx < 15360) {
      int ch = idx & 31, rem = idx >> 5;
      int ic = rem / 15, k = rem % 15;
      wp1T[idx] = p1_w[(ch * 32 + ic) * 15 + k];
    }
    if (idx < 256) {
      int c = idx;
      float sa = bn1_g[c] * rsqrtf(bn1_v[c] + 1e-3f);
      float ba = bn1_b[c] - bn1_m[c] * sa;
      float sg = bn1_g[c + 256] * rsqrtf(bn1_v[c + 256] + 1e-3f);
      float bg = bn1_b[c + 256] - bn1_m[c + 256] * sg;
      bnp[c] = make_float4(sa, ba, sg, bg);
    }
  }
}

// ============ K0b: transpose+cvt x -> xT bf16 [t][ci], + xx (f32 exact) ============
// grid (64 t-tiles of 64, 16 b), 256 thr. Two ci-halves of 128 through 33KB LDS.
__global__ __launch_bounds__(256) void k0b_tr(
    const float* __restrict__ x, const float* __restrict__ w1x1,
    short* __restrict__ xT, float* __restrict__ xx) {
  int t0 = blockIdx.x * 64;
  int b = blockIdx.y;
  __shared__ float ls[64][129];
  int tid = threadIdx.x;
  const float* xb = x + (size_t)b * (CIN * TN);
  float xacc = 0.f;
  for (int half = 0; half < 2; ++half) {
    if (half) __syncthreads();
#pragma unroll
    for (int s = 0; s < 8; ++s) {
      int idx = tid + s * 256;             // 0..2047
      int ci = idx >> 4, tc = idx & 15;
      float4 v = *(const float4*)(xb + (size_t)(half * 128 + ci) * TN + t0 + tc * 4);
      ls[tc * 4 + 0][ci] = v.x;
      ls[tc * 4 + 1][ci] = v.y;
      ls[tc * 4 + 2][ci] = v.z;
      ls[tc * 4 + 3][ci] = v.w;
    }
    __syncthreads();
    if (tid < 64) {
#pragma unroll 4
      for (int k = 0; k < 128; ++k)
        xacc = fmaf(ls[tid][k], w1x1[half * 128 + k], xacc);
    }
#pragma unroll
    for (int s = 0; s < 4; ++s) {
      int o = tid + s * 256;               // 0..1023
      int ci8 = o & 15, t = o >> 4;
      s16x8 pk;
#pragma unroll
      for (int i = 0; i < 8; ++i) {
        __hip_bfloat16 hv = __float2bfloat16(ls[t][ci8 * 8 + i]);
        pk[i] = *(short*)&hv;
      }
      *(s16x8*)(xT + ((size_t)(b * TN) + t0 + t) * 256 + half * 128 + ci8 * 8) = pk;
    }
  }
  if (tid < 64) xx[b * TN + t0 + tid] = xacc;
}

// ========== K1: bf16 MFMA GEMM + BN + GLU ==========
// grid flat 2048 = (4 nblk, 32 t-tiles of 128, 16 b), 256 thr = 4 waves, 64x64/wave.
__global__ __launch_bounds__(256) void k1_mfma(
    const short* __restrict__ xT, const short* __restrict__ wBpk,
    const float4* __restrict__ bnp, __hip_bfloat16* __restrict__ featT) {
  int f = blockIdx.x + 4 * (blockIdx.y + 32 * blockIdx.z);  // 0..2047
  int w = (f & 7) * 256 + (f >> 3);        // XCD-bijective: A-tile sharers on one XCD
  int nblk = w & 3, ty = (w >> 2) & 31, b = w >> 7;
  int t0 = ty * 128;
  int tid = threadIdx.x;
  int l = tid & 63, wv = tid >> 6;
  int wm = wv & 1, wn = wv >> 1;
  int tb = t0 + wm * 64;
  int nb16 = nblk * 8 + wn * 4;            // n16 base (4 frags of 16 cols)

  f32x4 acc[4][4];
#pragma unroll
  for (int i = 0; i < 4; ++i)
#pragma unroll
    for (int j = 0; j < 4; ++j) acc[i][j] = (f32x4){0.f, 0.f, 0.f, 0.f};

  const short* arow = xT + ((size_t)(b * TN) + tb + (l & 15)) * 256 + (l >> 4) * 8;
  const short* wrow = wBpk + l * 8;

#pragma unroll 2
  for (int ks = 0; ks < 8; ++ks) {
    s16x8 af[4], bf[4];
#pragma unroll
    for (int mf = 0; mf < 4; ++mf)
      af[mf] = *(const s16x8*)(arow + mf * 16 * 256 + ks * 32);
#pragma unroll
    for (int nf = 0; nf < 4; ++nf)
      bf[nf] = *(const s16x8*)(wrow + (size_t)(nb16 + nf) * 4096 + ks * 512);
#pragma unroll
    for (int mf = 0; mf < 4; ++mf)
#pragma unroll
      for (int nf = 0; nf < 4; ++nf)
        acc[mf][nf] = __builtin_amdgcn_mfma_f32_16x16x32_bf16(
            af[mf], bf[nf], acc[mf][nf], 0, 0, 0);
  }

  // epilogue: BN + GLU (packed col j pairs with j+32 -> frag nf vs nf+2, same lane)
  int cb = (nblk * 2 + wn) * 32;
  size_t base = ((size_t)b * TN + tb);
#pragma unroll
  for (int nf = 0; nf < 2; ++nf) {
    float4 bn = bnp[cb + nf * 16 + (l & 15)];
    int c = cb + nf * 16 + (l & 15);
#pragma unroll
    for (int mf = 0; mf < 4; ++mf) {
#pragma unroll
      for (int r = 0; r < 4; ++r) {
        float a = acc[mf][nf][r], g = acc[mf][nf + 2][r];
        float av = fmaf(a, bn.x, bn.y);
        float gv = fmaf(g, bn.z, bn.w);
        float fv = av / (1.f + __expf(-gv));
        int t = tb + mf * 16 + (l >> 4) * 4 + r;
        featT[(base + (t - tb)) * 0 + ((size_t)b * TN + t) * 256 + c] = __float2bfloat16(fv);
      }
    }
  }
}

// ========== K2: fused predictor (p0->bn->silu->p1->bn->silu->p2->sigmoid) ==========
__global__ __launch_bounds__(256) void k2_pred(
    const float* __restrict__ xx,
    const float* __restrict__ wp0T, const float* __restrict__ p0_b,
    const float* __restrict__ p0g, const float* __restrict__ p0bb,
    const float* __restrict__ p0m, const float* __restrict__ p0v,
    const float* __restrict__ wp1T, const float* __restrict__ p1_b,
    const float* __restrict__ p1g, const float* __restrict__ p1bb,
    const float* __restrict__ p1m, const float* __restrict__ p1v,
    const float* __restrict__ p2_w, const float* __restrict__ p2_b,
    const float* __restrict__ norm_mean,
    float* __restrict__ wts, float* __restrict__ mvr) {
  int t0 = blockIdx.x * 128;
  int b = blockIdx.y;
  __shared__ float xin[2][186];   // t in [t0-29, t0+157)
  __shared__ float h0s[32][176];  // t = t0-14+i, valid i<156
  __shared__ float h1s[32][142];  // t = t0-7+i,  i<142
  int tid = threadIdx.x;
  for (int idx = tid; idx < 186; idx += 256) {
    int t = t0 - 29 + idx;
    float v = (t >= 0 && t < TN) ? xx[b * TN + t] : 0.f;
    xin[0][idx] = v;
    xin[1][idx] = v * v;
  }
  __syncthreads();
  {  // p0: K=31, 2 in-ch
    int ch = tid & 31, tq = tid >> 5;
    float sc = p0g[ch] * rsqrtf(p0v[ch] + 1e-5f);
    float mb = p0m[ch], bbn = p0bb[ch], bias = p0_b[ch];
    for (int i = tq; i < 156; i += 8) {
      float a = bias;
#pragma unroll
      for (int ic = 0; ic < 2; ++ic)
#pragma unroll
        for (int k = 0; k < 31; ++k)
          a = fmaf(wp0T[(ic * 31 + k) * 32 + ch], xin[ic][i + k], a);
      float v = (a - mb) * sc + bbn;
      h0s[ch][i] = v / (1.f + __expf(-v));
    }
  }
  __syncthreads();
  {  // p1: K=15, 32 in-ch (row in regs)
    int ch = tid & 31, tq = tid >> 5;
    int i0 = tq * 20;
    float sc = p1g[ch] * rsqrtf(p1v[ch] + 1e-5f);
    float mb = p1m[ch], bbn = p1bb[ch], bias = p1_b[ch];
    float a[20];
#pragma unroll
    for (int j = 0; j < 20; ++j) a[j] = bias;
    for (int ic = 0; ic < 32; ++ic) {
      float r[36];
#pragma unroll
      for (int q = 0; q < 9; ++q) {
        float4 t4 = *(const float4*)(&h0s[ic][i0 + q * 4]);
        r[q * 4 + 0] = t4.x; r[q * 4 + 1] = t4.y;
        r[q * 4 + 2] = t4.z; r[q * 4 + 3] = t4.w;
      }
      float w[15];
#pragma unroll
      for (int k = 0; k < 15; ++k) w[k] = wp1T[(ic * 15 + k) * 32 + ch];
#pragma unroll
      for (int j = 0; j < 20; ++j)
#pragma unroll
        for (int k = 0; k < 15; ++k) a[j] = fmaf(w[k], r[j + k], a[j]);
    }
#pragma unroll
    for (int j = 0; j < 20; ++j) {
      int i = i0 + j;
      if (i < 142) {
        float v = (a[j] - mb) * sc + bbn;
        h1s[ch][i] = v / (1.f + __expf(-v));
      }
    }
  }
  __syncthreads();
  {  // p2: K=15, 2 out-ch -> sigmoids
    int ch = tid >> 7, i = tid & 127;
    float a = p2_b[ch];
    for (int ic = 0; ic < 32; ++ic)
#pragma unroll
      for (int k = 0; k < 15; ++k)
        a = fmaf(p2_w[(ch * 32 + ic) * 15 + k], h1s[ic][i + k], a);
    float s = 1.f / (1.f + __expf(-a));
    int t = t0 + i;
    if (ch == 0) wts[b * TN + t] = s;
    else         mvr[b * TN + t] = s * norm_mean[0];
  }
}

// ========== K3: per-batch renorm + cumsum + first_t ==========
__global__ __launch_bounds__(256) void k3_scan(const float* __restrict__ mvr,
                                               float* __restrict__ poses,
                                               int* __restrict__ firstT) {
  int b = blockIdx.x, tid = threadIdx.x;
  __shared__ float csum[256];
  __shared__ int shlast;
  float v[16];
  const float* src = mvr + b * TN + tid * 16;
  float run = 0.f;
#pragma unroll
  for (int j = 0; j < 16; ++j) { run += src[j]; v[j] = run; }
  csum[tid] = run;
  __syncthreads();
  for (int off = 1; off < 256; off <<= 1) {
    float tv = (tid >= off) ? csum[tid - off] : 0.f;
    __syncthreads();
    csum[tid] += tv;
    __syncthreads();
  }
  float incl = csum[tid];
  float total = csum[255];
  float excl = incl - run;
  __syncthreads();
  float rn = total * (1.0f / 4096.0f);
  float inv = (rn > 1.0f) ? 1.0f / rn : 1.0f;
  float p16[16];
  float* pd = poses + b * TN + tid * 16;
#pragma unroll
  for (int j = 0; j < 16; ++j) { p16[j] = (excl + v[j]) * inv; pd[j] = p16[j]; }
  csum[tid] = p16[15];
  __syncthreads();
  int* ft = firstT + b * FTS;
  int prevf = (tid == 0) ? -1 : min((int)floorf(csum[tid - 1]), 4220);
  int f = prevf;
#pragma unroll
  for (int j = 0; j < 16; ++j) {
    f = min((int)floorf(p16[j]), 4220);
    for (int l = prevf + 1; l <= f; ++l) ft[l] = tid * 16 + j;
    prevf = f;
  }
  if (tid == 255) shlast = f;
  __syncthreads();
  for (int l = shlast + 1 + tid; l < FTS; l += 256) ft[l] = TN;
}

// ========== K4: gather-formulated scatter pool (atomic-free) ==========
__global__ __launch_bounds__(256) void k4_gather(
    const __hip_bfloat16* __restrict__ featT, const float* __restrict__ wts,
    const float* __restrict__ poses, const int* __restrict__ firstT,
    float* __restrict__ out) {
  int l0 = blockIdx.x * 16;
  int b = blockIdx.y;
  __shared__ float acc[16][258];
  int tid = threadIdx.x;
  for (int idx = tid; idx < 16 * 258; idx += 256) ((float*)acc)[idx] = 0.f;
  const int* ft = firstT + b * FTS;
  int ts = ft[l0 == 0 ? 0 : l0 - 1];
  int te = ft[l0 + 16];
  __syncthreads();
  int c = tid;
  for (int t = ts; t < te; ++t) {
    float p = poses[b * TN + t];
    float wg = wts[b * TN + t];
    float fv = __bfloat162float(featT[((size_t)b * TN + t) * 256 + c]);
    int fi = (int)floorf(p);
    float w2 = p - (float)fi;
    float w1 = 1.f - w2;
    float fw = fv * wg;
    int r1 = fi - l0;
    if (r1 >= 0 && r1 < 16) acc[r1][c] += w1 * fw;
    int r2 = r1 + 1;
    if (r2 >= 0 && r2 < 16) acc[r2][c] += w2 * fw;
  }
  __syncthreads();
  for (int idx = tid; idx < 4096; idx += 256) {
    int c2 = idx >> 4, r = idx & 15;
    int l = l0 + r;
    if (l < LOUT) out[((size_t)b * 256 + c2) * LOUT + l] = acc[r][c2];
  }
}

// ======================= launch =======================
extern "C" void kernel_launch(void* const* d_in, const int* in_sizes, int n_in,
                              void* d_out, int out_size, void* d_ws, size_t ws_size,
                              hipStream_t stream) {
  const float* x       = (const float*)d_in[0];
  const float* conv1_w = (const float*)d_in[1];
  const float* bn1_g   = (const float*)d_in[2];
  const float* bn1_b   = (const float*)d_in[3];
  const float* bn1_m   = (const float*)d_in[4];
  const float* bn1_v   = (const float*)d_in[5];
  const float* w1x1    = (const float*)d_in[6];
  const float* p0_w    = (const float*)d_in[7];
  const float* p0_b    = (const float*)d_in[8];
  const float* p0g     = (const float*)d_in[9];
  const float* p0bb    = (const float*)d_in[10];
  const float* p0m     = (const float*)d_in[11];
  const float* p0v     = (const float*)d_in[12];
  const float* p1_w    = (const float*)d_in[13];
  const float* p1_b    = (const float*)d_in[14];
  const float* p1g     = (const float*)d_in[15];
  const float* p1bb    = (const float*)d_in[16];
  const float* p1m     = (const float*)d_in[17];
  const float* p1v     = (const float*)d_in[18];
  const float* p2_w    = (const float*)d_in[19];
  const float* p2_b    = (const float*)d_in[20];
  const float* nmean   = (const float*)d_in[21];

  char* ws = (char*)d_ws;
  __hip_bfloat16* featT = (__hip_bfloat16*)ws;
  short* wBpk   = (short*)(ws + 33554432);
  float4* bnp   = (float4*)(ws + 33816576);
  float* wp0T   = (float*)(ws + 33820672);
  float* wp1T   = (float*)(ws + 33828864);
  float* xx     = (float*)(ws + 33890304);
  float* wts    = (float*)(ws + 34152448);
  float* mvr    = (float*)(ws + 34414592);
  float* poses  = (float*)(ws + 34676736);
  int*   firstT = (int*)  (ws + 34938880);
  float* out    = (float*)d_out;
  short* xT     = (short*)d_out;   // scratch; K4 rewrites every element of d_out

  k0_prep<<<dim3(572), dim3(256), 0, stream>>>(conv1_w, p0_w, p1_w, bn1_g, bn1_b,
                                               bn1_m, bn1_v, wBpk, bnp, wp0T, wp1T);
  k0b_tr<<<dim3(64, 16), dim3(256), 0, stream>>>(x, w1x1, xT, xx);
  k1_mfma<<<dim3(4, 32, 16), dim3(256), 0, stream>>>(xT, wBpk, bnp, featT);
  k2_pred<<<dim3(32, 16), dim3(256), 0, stream>>>(xx, wp0T, p0_b, p0g, p0bb, p0m, p0v,
                                                  wp1T, p1_b, p1g, p1bb, p1m, p1v,
                                                  p2_w, p2_b, nmean, wts, mvr);
  k3_scan<<<dim3(16), dim3(256), 0, stream>>>(mvr, poses, firstT);
  k4_gather<<<dim3(257, 16), dim3(256), 0, stream>>>(featT, wts, poses, firstT, out);
}